// Round 3
// baseline (410.601 us; speedup 1.0000x reference)
//
#include <hip/hip_runtime.h>

// NeuS-style renderer sampling (all fp32):
//  inputs: ray_dirs (1,262144,3), cam_loc (1,3), t_rand (262144,64)
//  outputs (concat): new_samples (P,32,3), z_samples (P,32), weights (P,63)
//
// Structure (round 3): THREAD-per-ray. All cross-step ops are sequential
// scalars per thread; steps[64] + w[63] held in registers via full unroll
// (static indices only). Importance sampling = monotone merge-walk over
// (sorted cdf) x (sorted u grid) — no searchsorted, no shuffles, no LDS.
// mean_si reduction: two-stage (block partials -> final block), no atomics.

static constexpr int NSTEPS = 64;
static constexpr int NIMP   = 32;

// ---------- pass 1a: per-block partial sums over hit rays ----------
__global__ __launch_bounds__(256) void si_partial_kernel(
    const float* __restrict__ rd, const float* __restrict__ cam,
    float* __restrict__ partial, int P)
{
  float cx = cam[0], cy = cam[1], cz = cam[2];
  float c2m = cx*cx + cy*cy + cz*cz - 1.0f;   // |cam|^2 - R^2, R=1
  float s0 = 0.f, s1 = 0.f, cnt = 0.f;
  int stride = gridDim.x * blockDim.x;
  for (int p = blockIdx.x * blockDim.x + threadIdx.x; p < P; p += stride){
    float dx = rd[3*p+0], dy = rd[3*p+1], dz = rd[3*p+2];
    float rcd = dx*cx + dy*cy + dz*cz;
    float under = rcd*rcd - c2m;
    if (under > 0.f){
      float sq = sqrtf(under);
      s0 += -sq - rcd; s1 += sq - rcd; cnt += 1.f;
    }
  }
  #pragma unroll
  for (int off = 32; off > 0; off >>= 1){
    s0  += __shfl_down(s0,  off, 64);
    s1  += __shfl_down(s1,  off, 64);
    cnt += __shfl_down(cnt, off, 64);
  }
  __shared__ float sh[3][4];
  int w = threadIdx.x >> 6;
  if ((threadIdx.x & 63) == 0){ sh[0][w] = s0; sh[1][w] = s1; sh[2][w] = cnt; }
  __syncthreads();
  if (threadIdx.x == 0){
    partial[blockIdx.x*3+0] = sh[0][0]+sh[0][1]+sh[0][2]+sh[0][3];
    partial[blockIdx.x*3+1] = sh[1][0]+sh[1][1]+sh[1][2]+sh[1][3];
    partial[blockIdx.x*3+2] = sh[2][0]+sh[2][1]+sh[2][2]+sh[2][3];
  }
}

// ---------- pass 1b: reduce partials -> ws[0..2] ----------
__global__ __launch_bounds__(256) void si_final_kernel(
    const float* __restrict__ partial, float* __restrict__ ws, int nblk)
{
  float s0 = 0.f, s1 = 0.f, cnt = 0.f;
  for (int b = threadIdx.x; b < nblk; b += 256){
    s0 += partial[3*b+0]; s1 += partial[3*b+1]; cnt += partial[3*b+2];
  }
  #pragma unroll
  for (int off = 32; off > 0; off >>= 1){
    s0  += __shfl_down(s0,  off, 64);
    s1  += __shfl_down(s1,  off, 64);
    cnt += __shfl_down(cnt, off, 64);
  }
  __shared__ float sh[3][4];
  int w = threadIdx.x >> 6;
  if ((threadIdx.x & 63) == 0){ sh[0][w] = s0; sh[1][w] = s1; sh[2][w] = cnt; }
  __syncthreads();
  if (threadIdx.x == 0){
    ws[0] = sh[0][0]+sh[0][1]+sh[0][2]+sh[0][3];
    ws[1] = sh[1][0]+sh[1][1]+sh[1][2]+sh[1][3];
    ws[2] = sh[2][0]+sh[2][1]+sh[2][2]+sh[2][3];
  }
}

// ---------- pass 2: thread per ray ----------
__global__ __launch_bounds__(256) void render_main_kernel(
    const float* __restrict__ rd, const float* __restrict__ cam,
    const float* __restrict__ tr, const float* __restrict__ ws,
    float* __restrict__ out, int P)
{
  int p = blockIdx.x * blockDim.x + threadIdx.x;
  if (p >= P) return;

  float cx = cam[0], cy = cam[1], cz = cam[2];
  float c2m = cx*cx + cy*cy + cz*cz - 1.0f;
  float dx = rd[3*p+0], dy = rd[3*p+1], dz = rd[3*p+2];
  float rcd = dx*cx + dy*cy + dz*cz;
  float under = rcd*rcd - c2m;
  float si0, si1;
  if (under > 0.f){
    float sq = sqrtf(under);
    si0 = -sq - rcd; si1 = sq - rcd;
  } else {
    float nh = fmaxf(ws[2], 1.0f);
    si0 = ws[0] / nh; si1 = ws[1] / nh;
  }
  float min_d = fmaxf(si0, 0.f), max_d = fmaxf(si1, 0.f);
  float range = max_d - min_d;
  float sdist = range * (1.0f / NSTEPS);

  // steps[64] in registers (static indices only)
  float steps[NSTEPS];
  const float4* tr4 = (const float4*)(tr + (size_t)p * NSTEPS);
  #pragma unroll
  for (int q = 0; q < 16; q++){
    float4 v = tr4[q];
    steps[4*q+0] = fmaf(range, (float)(4*q+0) * (1.0f/63.0f), min_d) + (v.x - 0.5f) * sdist;
    steps[4*q+1] = fmaf(range, (float)(4*q+1) * (1.0f/63.0f), min_d) + (v.y - 0.5f) * sdist;
    steps[4*q+2] = fmaf(range, (float)(4*q+2) * (1.0f/63.0f), min_d) + (v.z - 0.5f) * sdist;
    steps[4*q+3] = fmaf(range, (float)(4*q+3) * (1.0f/63.0f), min_d) + (v.w - 0.5f) * sdist;
  }

  // weights: rolling sigmoid + running cumprod
  const float inv_s = 20.085536923187668f;   // exp(0.3*10)
  float w[NSTEPS-1];
  float T = 0.f, trans = 1.f;
  float px = fmaf(steps[0], dx, cx), py = fmaf(steps[0], dy, cy), pz = fmaf(steps[0], dz, cz);
  float c0 = 1.0f / (1.0f + __expf(-(sqrtf(px*px+py*py+pz*pz) - 0.5f) * inv_s));
  #pragma unroll
  for (int j = 0; j < NSTEPS-1; j++){
    float qx = fmaf(steps[j+1], dx, cx), qy = fmaf(steps[j+1], dy, cy), qz = fmaf(steps[j+1], dz, cz);
    float c1 = 1.0f / (1.0f + __expf(-(sqrtf(qx*qx+qy*qy+qz*qz) - 0.5f) * inv_s));
    float a = (c0 - c1 + 1e-8f) / (c0 + 1e-8f);
    a = fminf(fmaxf(a, 0.f), 1.0f);
    float wj = a * trans;
    w[j] = wj;
    T += wj;
    trans *= (1.0f - a + 1e-7f);
    c0 = c1;
  }
  T += 63.0f * 1e-8f;
  float invT = 1.0f / T;

  // store weights (scatter; all bytes of each line written -> L2 combines)
  float* wout = out + (size_t)P*128 + (size_t)p*63;
  #pragma unroll
  for (int j = 0; j < NSTEPS-1; j++) wout[j] = w[j];

  // importance sampling: merge-walk of sorted u grid through sorted cdf
  float* zout = out + (size_t)P*96 + (size_t)p*32;
  float* nout = out + (size_t)p*96;
  int i = 0;
  float cdf_m = 0.f;
  #pragma unroll
  for (int m = 0; m < NSTEPS-1; m++){
    float cdf_n = cdf_m + (w[m] + 1e-8f) * invT;
    while (i < NIMP){
      float u = (float)(2*i + 1) * (1.0f / 64.0f);
      if (!(u < cdf_n)) break;              // 'right' searchsorted: u==cdf -> next bin
      float denom = cdf_n - cdf_m;
      if (denom < 1e-8f) denom = 1.0f;
      float t = (u - cdf_m) / denom;
      float z = fmaf(t, steps[m+1] - steps[m], steps[m]);
      zout[i] = z;
      nout[3*i+0] = fmaf(z, dx, cx);
      nout[3*i+1] = fmaf(z, dy, cy);
      nout[3*i+2] = fmaf(z, dz, cz);
      i++;
    }
    cdf_m = cdf_n;
  }
  // tail guard (u >= cdf[63] by rounding): below=above=63 -> z = steps[63]
  float zl = steps[NSTEPS-1];
  float nx = fmaf(zl, dx, cx), ny = fmaf(zl, dy, cy), nz = fmaf(zl, dz, cz);
  while (i < NIMP){
    zout[i] = zl;
    nout[3*i+0] = nx; nout[3*i+1] = ny; nout[3*i+2] = nz;
    i++;
  }
}

extern "C" void kernel_launch(void* const* d_in, const int* in_sizes, int n_in,
                              void* d_out, int out_size, void* d_ws, size_t ws_size,
                              hipStream_t stream) {
  const float* rd  = (const float*)d_in[0];
  const float* cam = (const float*)d_in[1];
  const float* tr  = (const float*)d_in[2];
  float* out = (float*)d_out;
  float* ws  = (float*)d_ws;       // ws[0..2] = mean_si sums; ws+8.. = partials
  const int P = in_sizes[0] / 3;   // 262144 rays

  const int RBLK = 256;            // partial-reduction blocks
  si_partial_kernel<<<RBLK, 256, 0, stream>>>(rd, cam, ws + 8, P);
  si_final_kernel<<<1, 256, 0, stream>>>(ws + 8, ws, RBLK);
  render_main_kernel<<<(P + 255) / 256, 256, 0, stream>>>(rd, cam, tr, ws, out, P);
}

// Round 4
// 316.936 us; speedup vs baseline: 1.2955x; 1.2955x over previous
//
#include <hip/hip_runtime.h>

// NeuS-style renderer sampling (all fp32):
//  inputs: ray_dirs (1,262144,3), cam_loc (1,3), t_rand (262144,64)
//  outputs (concat): new_samples (P,32,3), z_samples (P,32), weights (P,63)
//
// Round 4: thread-per-ray compute + LDS-staged, block-coalesced stores.
// Each block's 256 rays own contiguous output regions; stage into a 36 KB
// LDS buffer and stream out with dwordx4 so every L2 line is written whole
// (round 3 showed 2.8x write amplification from lane-scattered stores).
// steps[] are recomputed from t_rand in the merge-walk pass to keep VGPRs
// under 128 (launch_bounds(256,4) -> 4 blocks/CU; LDS 36 KB -> 4 blocks/CU).

static constexpr int NSTEPS = 64;
static constexpr int NIMP   = 32;

// ---------- pass 1a: per-block partial sums over hit rays ----------
__global__ __launch_bounds__(256) void si_partial_kernel(
    const float* __restrict__ rd, const float* __restrict__ cam,
    float* __restrict__ partial, int P)
{
  float cx = cam[0], cy = cam[1], cz = cam[2];
  float c2m = cx*cx + cy*cy + cz*cz - 1.0f;   // |cam|^2 - R^2, R=1
  float s0 = 0.f, s1 = 0.f, cnt = 0.f;
  int stride = gridDim.x * blockDim.x;
  for (int p = blockIdx.x * blockDim.x + threadIdx.x; p < P; p += stride){
    float dx = rd[3*p+0], dy = rd[3*p+1], dz = rd[3*p+2];
    float rcd = dx*cx + dy*cy + dz*cz;
    float under = rcd*rcd - c2m;
    if (under > 0.f){
      float sq = sqrtf(under);
      s0 += -sq - rcd; s1 += sq - rcd; cnt += 1.f;
    }
  }
  #pragma unroll
  for (int off = 32; off > 0; off >>= 1){
    s0  += __shfl_down(s0,  off, 64);
    s1  += __shfl_down(s1,  off, 64);
    cnt += __shfl_down(cnt, off, 64);
  }
  __shared__ float sh[3][4];
  int w = threadIdx.x >> 6;
  if ((threadIdx.x & 63) == 0){ sh[0][w] = s0; sh[1][w] = s1; sh[2][w] = cnt; }
  __syncthreads();
  if (threadIdx.x == 0){
    partial[blockIdx.x*3+0] = sh[0][0]+sh[0][1]+sh[0][2]+sh[0][3];
    partial[blockIdx.x*3+1] = sh[1][0]+sh[1][1]+sh[1][2]+sh[1][3];
    partial[blockIdx.x*3+2] = sh[2][0]+sh[2][1]+sh[2][2]+sh[2][3];
  }
}

// ---------- pass 1b: reduce partials -> ws[0..2] ----------
__global__ __launch_bounds__(256) void si_final_kernel(
    const float* __restrict__ partial, float* __restrict__ ws, int nblk)
{
  float s0 = 0.f, s1 = 0.f, cnt = 0.f;
  for (int b = threadIdx.x; b < nblk; b += 256){
    s0 += partial[3*b+0]; s1 += partial[3*b+1]; cnt += partial[3*b+2];
  }
  #pragma unroll
  for (int off = 32; off > 0; off >>= 1){
    s0  += __shfl_down(s0,  off, 64);
    s1  += __shfl_down(s1,  off, 64);
    cnt += __shfl_down(cnt, off, 64);
  }
  __shared__ float sh[3][4];
  int w = threadIdx.x >> 6;
  if ((threadIdx.x & 63) == 0){ sh[0][w] = s0; sh[1][w] = s1; sh[2][w] = cnt; }
  __syncthreads();
  if (threadIdx.x == 0){
    ws[0] = sh[0][0]+sh[0][1]+sh[0][2]+sh[0][3];
    ws[1] = sh[1][0]+sh[1][1]+sh[1][2]+sh[1][3];
    ws[2] = sh[2][0]+sh[2][1]+sh[2][2]+sh[2][3];
  }
}

// ---------- pass 2: thread per ray, LDS-staged coalesced stores ----------
// LDS map: [0..8191]  weights staging (8064 used) then zbuf[256][32]
//          [8192..9215] dbuf[256][4] (ray dirs, stride 4)
__global__ __launch_bounds__(256, 4) void render_main_kernel(
    const float* __restrict__ rd, const float* __restrict__ cam,
    const float* __restrict__ tr, const float* __restrict__ ws,
    float* __restrict__ out, int P)
{
  __shared__ float lds[9216];
  const int tid  = threadIdx.x;
  const int blk  = blockIdx.x;
  const int ray0 = blk * 256;
  const int nrays = min(256, P - ray0);
  const int p = min(ray0 + tid, P - 1);     // clamp; stores are range-guarded

  float cx = cam[0], cy = cam[1], cz = cam[2];
  float c2m = cx*cx + cy*cy + cz*cz - 1.0f;
  float dx = rd[3*p+0], dy = rd[3*p+1], dz = rd[3*p+2];
  lds[8192 + tid*4 + 0] = dx;               // dbuf (region disjoint from staging)
  lds[8192 + tid*4 + 1] = dy;
  lds[8192 + tid*4 + 2] = dz;

  float rcd = dx*cx + dy*cy + dz*cz;
  float under = rcd*rcd - c2m;
  float si0, si1;
  if (under > 0.f){
    float sq = sqrtf(under);
    si0 = -sq - rcd; si1 = sq - rcd;
  } else {
    float nh = fmaxf(ws[2], 1.0f);
    si0 = ws[0] / nh; si1 = ws[1] / nh;
  }
  float min_d = fmaxf(si0, 0.f), max_d = fmaxf(si1, 0.f);
  float range = max_d - min_d;
  float sdist = range * (1.0f / NSTEPS);

  const float4* tr4 = (const float4*)(tr + (size_t)p * NSTEPS);
  const float inv_s = 20.085536923187668f;  // exp(0.3*10)

  // ---- pass A: weights w[63] in regs + total T (steps on the fly) ----
  float w[NSTEPS-1];
  float T = 0.f, trans = 1.f;
  float4 v = tr4[0];
  float st = min_d + (v.x - 0.5f) * sdist;  // step 0 (linspace term = 0)
  float px = fmaf(st,dx,cx), py = fmaf(st,dy,cy), pz = fmaf(st,dz,cz);
  float c0 = 1.0f / (1.0f + __expf(-(sqrtf(px*px+py*py+pz*pz) - 0.5f) * inv_s));
  #pragma unroll
  for (int j = 1; j < NSTEPS; j++){
    if ((j & 3) == 0) v = tr4[j >> 2];
    float tj = ((j&3)==0) ? v.x : ((j&3)==1) ? v.y : ((j&3)==2) ? v.z : v.w;
    float sn = fmaf(range, (float)j * (1.0f/63.0f), min_d) + (tj - 0.5f) * sdist;
    float qx = fmaf(sn,dx,cx), qy = fmaf(sn,dy,cy), qz = fmaf(sn,dz,cz);
    float c1 = 1.0f / (1.0f + __expf(-(sqrtf(qx*qx+qy*qy+qz*qz) - 0.5f) * inv_s));
    float a = (c0 - c1 + 1e-8f) / (c0 + 1e-8f);
    a = fminf(fmaxf(a, 0.f), 1.0f);
    float wj = a * trans;
    w[j-1] = wj; T += wj;
    trans *= (1.0f - a + 1e-7f);
    c0 = c1;
  }
  T += 63.0f * 1e-8f;
  float invT = 1.0f / T;

  // ---- weights: stage+store in two 128-ray chunks (coalesced dwordx4) ----
  // chunk 0
  if (tid < 128){
    #pragma unroll
    for (int j = 0; j < 63; j++) lds[tid*63 + j] = w[j];
  }
  __syncthreads();
  {
    int cnt0 = min(128, nrays);
    if (cnt0 > 0){
      size_t base = (size_t)P*128 + (size_t)ray0*63;
      if (cnt0 == 128){
        float4* gw = (float4*)(out + base);
        const float4* lw = (const float4*)lds;
        #pragma unroll
        for (int it = 0; it < 8; it++){
          int idx = it*256 + tid;
          if (idx < 2016) gw[idx] = lw[idx];
        }
      } else {
        int dwn = cnt0 * 63;
        for (int idx = tid; idx < dwn; idx += 256) out[base + idx] = lds[idx];
      }
    }
  }
  __syncthreads();
  // chunk 1
  if (tid >= 128){
    #pragma unroll
    for (int j = 0; j < 63; j++) lds[(tid-128)*63 + j] = w[j];
  }
  __syncthreads();
  {
    int cnt1 = nrays - 128;
    if (cnt1 > 0){
      size_t base = (size_t)P*128 + ((size_t)ray0 + 128)*63;
      if (cnt1 == 128){
        float4* gw = (float4*)(out + base);
        const float4* lw = (const float4*)lds;
        #pragma unroll
        for (int it = 0; it < 8; it++){
          int idx = it*256 + tid;
          if (idx < 2016) gw[idx] = lw[idx];
        }
      } else {
        int dwn = cnt1 * 63;
        for (int idx = tid; idx < dwn; idx += 256) out[base + idx] = lds[idx];
      }
    }
  }
  __syncthreads();

  // ---- pass B: merge-walk; z -> zbuf in LDS (steps recomputed from tr) ----
  {
    float4 v2 = tr4[0];
    float sm = min_d + (v2.x - 0.5f) * sdist;
    float cdfm = 0.f;
    int i = 0;
    #pragma unroll
    for (int m = 0; m < NSTEPS-1; m++){
      int j = m + 1;
      if ((j & 3) == 0) v2 = tr4[j >> 2];
      float tj = ((j&3)==0) ? v2.x : ((j&3)==1) ? v2.y : ((j&3)==2) ? v2.z : v2.w;
      float sn = fmaf(range, (float)j * (1.0f/63.0f), min_d) + (tj - 0.5f) * sdist;
      float cdfn = cdfm + (w[m] + 1e-8f) * invT;
      while (i < NIMP){
        float u = (float)(2*i + 1) * (1.0f / 64.0f);
        if (!(u < cdfn)) break;             // searchsorted 'right'
        float denom = cdfn - cdfm;
        if (denom < 1e-8f) denom = 1.0f;
        float t = (u - cdfm) / denom;
        lds[tid*32 + i] = fmaf(t, sn - sm, sm);
        i++;
      }
      cdfm = cdfn; sm = sn;
    }
    while (i < NIMP){ lds[tid*32 + i] = sm; i++; }   // tail: z = steps[63]
  }
  __syncthreads();

  // ---- z_samples: coalesced dwordx4 (8192 dwords contiguous per block) ----
  {
    int nz4 = nrays * 8;
    float4* gz = (float4*)(out + (size_t)P*96 + (size_t)ray0*32);
    const float4* zb4 = (const float4*)lds;
    #pragma unroll
    for (int it = 0; it < 8; it++){
      int idx = it*256 + tid;
      if (idx < nz4) gz[idx] = zb4[idx];
    }
  }

  // ---- new_samples: computed at store time from zbuf+dbuf, coalesced ----
  {
    int nn4 = nrays * 24;                    // 24 float4 per ray
    float4* gn = (float4*)(out + (size_t)ray0*96);
    #pragma unroll 4
    for (int it = 0; it < 24; it++){
      int idx4 = it*256 + tid;
      if (idx4 < nn4){
        int r   = idx4 / 24;
        int rem = idx4 - r*24;
        int e   = rem * 4;                   // element within ray region [0,96)
        int s   = e / 3;
        int c   = e - s*3;
        float4 o;
        float* op = &o.x;
        #pragma unroll
        for (int k = 0; k < 4; k++){
          float zz = lds[r*32 + s];
          float dd = lds[8192 + r*4 + c];
          float cc = (c == 0) ? cx : ((c == 1) ? cy : cz);
          op[k] = fmaf(zz, dd, cc);
          if (++c == 3){ c = 0; s++; }
        }
        gn[idx4] = o;
      }
    }
  }
}

extern "C" void kernel_launch(void* const* d_in, const int* in_sizes, int n_in,
                              void* d_out, int out_size, void* d_ws, size_t ws_size,
                              hipStream_t stream) {
  const float* rd  = (const float*)d_in[0];
  const float* cam = (const float*)d_in[1];
  const float* tr  = (const float*)d_in[2];
  float* out = (float*)d_out;
  float* ws  = (float*)d_ws;       // ws[0..2] = mean_si sums; ws+8.. = partials
  const int P = in_sizes[0] / 3;   // 262144 rays

  const int RBLK = 256;
  si_partial_kernel<<<RBLK, 256, 0, stream>>>(rd, cam, ws + 8, P);
  si_final_kernel<<<1, 256, 0, stream>>>(ws + 8, ws, RBLK);
  render_main_kernel<<<(P + 255) / 256, 256, 0, stream>>>(rd, cam, tr, ws, out, P);
}